// Round 21
// baseline (270.894 us; speedup 1.0000x reference)
//
#include <hip/hip_runtime.h>

typedef __bf16 bf16x8 __attribute__((ext_vector_type(8)));
typedef float f32x4 __attribute__((ext_vector_type(4)));
typedef float f32x16 __attribute__((ext_vector_type(16)));

static constexpr int Bb = 4, Ss = 2048, Ee = 1024, Hh = 16, DKk = 64, DVv = 128;
static constexpr int Mm = Bb * Ss;   // 8192
static constexpr int NQ = Hh * DKk;  // 1024
static constexpr int NV = Hh * DVv;  // 2048

#define MFMA16 __builtin_amdgcn_mfma_f32_16x16x32_bf16
#define MFMA32 __builtin_amdgcn_mfma_f32_32x32x16_bf16

#define GLL16(g, l) __builtin_amdgcn_global_load_lds(                        \
    (const __attribute__((address_space(1))) void*)(g),                      \
    (__attribute__((address_space(3))) void*)(l), 16, 0, 0)

#define SBAR()   asm volatile("s_barrier" ::: "memory")
#define SCHB()   __builtin_amdgcn_sched_barrier(0)
#define WLGKM0() do { asm volatile("s_waitcnt lgkmcnt(0)" ::: "memory"); SCHB(); } while (0)
#define WLGKM8() do { asm volatile("s_waitcnt lgkmcnt(8)" ::: "memory"); SCHB(); } while (0)
#define WVM(n)   asm volatile("s_waitcnt vmcnt(" #n ")" ::: "memory")

static __device__ __forceinline__ unsigned short f2b(float f) {
  unsigned int u = __float_as_uint(f);
  u += 0x7fffu + ((u >> 16) & 1u);
  return (unsigned short)(u >> 16);
}

__global__ __launch_bounds__(256) void cast_x_kernel(const float* __restrict__ in,
                                                     unsigned short* __restrict__ out, int n4) {
  int i = blockIdx.x * 256 + threadIdx.x;
  if (i >= n4) return;
  float4 v = reinterpret_cast<const float4*>(in)[i];
  ushort4 o;
  o.x = f2b(v.x); o.y = f2b(v.y); o.z = f2b(v.z); o.w = f2b(v.w);
  reinterpret_cast<ushort4*>(out)[i] = o;
}

// in: [Bt][R][C] f32  ->  out: [Bt][C][R] bf16
__global__ __launch_bounds__(256) void transpose_cast_kernel(const float* __restrict__ in,
                                                             unsigned short* __restrict__ out,
                                                             int R, int C) {
  __shared__ float tile[32][33];
  int c0 = blockIdx.x * 32, r0 = blockIdx.y * 32;
  const float* ip = in + (size_t)blockIdx.z * R * C;
  unsigned short* op = out + (size_t)blockIdx.z * R * C;
  int tx = threadIdx.x, ty = threadIdx.y;
#pragma unroll
  for (int i = 0; i < 32; i += 8)
    tile[ty + i][tx] = ip[(size_t)(r0 + ty + i) * C + (c0 + tx)];
  __syncthreads();
#pragma unroll
  for (int i = 0; i < 32; i += 8)
    op[(size_t)(c0 + ty + i) * R + (r0 + tx)] = f2b(tile[tx][ty + i]);
}

// ---------------------------------------------------------------------------
// gemm10: 256x256 tile, ONE phase per 64-K-tile; counted WVM(8) on staging AND
// counted lgkmcnt(8) on fragment reads: issue B(8)+A1(8)+A2(8) in pinned order,
// wait lgkm(8) -> B+A1 complete (in-order DS) while A2 drains under sec1 MFMAs.
// OUTMODE: 2 = bf16 Vt[B,H,DV,S]; 4 = fused QK head-major, Q pre-scaled.
// ---------------------------------------------------------------------------
template <int OUTMODE>
__global__ __launch_bounds__(512, 2) void gemm10_kernel(const unsigned short* __restrict__ A,
                                                        const unsigned short* __restrict__ BT,
                                                        const float* __restrict__ bias1,
                                                        const float* __restrict__ bias2,
                                                        void* __restrict__ out1,
                                                        void* __restrict__ out2,
                                                        int N, int K) {
  __shared__ unsigned short As0[256 * 64], As1[256 * 64];
  __shared__ unsigned short Bs0[256 * 64], Bs1[256 * 64];
  const int tid = threadIdx.x, wave = tid >> 6, lane = tid & 63;
  const int wm = wave >> 2, wn = wave & 3;
  const int l15 = lane & 15, lq = lane >> 4;
  const int nwg = gridDim.x, cpx = nwg >> 3;
  const int orig = (blockIdx.x & 7) * cpx + (blockIdx.x >> 3);  // XCD-contiguous
  const int bm = (orig & 31) << 8, bn = (orig >> 5) << 8;
  const int srow = tid >> 3;
  const int ssw = (((tid & 7) ^ (srow & 7)) << 3);
  const int rsw = l15 & 7;
  const int nIter = K >> 6;   // 64-K tiles

  f32x4 acc[8][4] = {};

#define LDAx(P, MI, KK) \
  (*reinterpret_cast<const bf16x8*>(&(P)[(size_t)((wm * 128 + (MI)*16 + l15) * 64) + (((((KK)*4 + lq)) ^ rsw) << 3)]))
#define LDBx(P, NI, KK) \
  (*reinterpret_cast<const bf16x8*>(&(P)[(size_t)((wn * 64 + (NI)*16 + l15) * 64) + (((((KK)*4 + lq)) ^ rsw) << 3)]))

  auto stA = [&](unsigned short* dst, int kt) {
#pragma unroll
    for (int k4 = 0; k4 < 4; ++k4)
      GLL16(A + (size_t)(bm + srow + k4 * 64) * K + kt * 64 + ssw,
            &dst[(size_t)(tid + k4 * 512) * 8]);
  };
  auto stB = [&](unsigned short* dst, int kt) {
#pragma unroll
    for (int k4 = 0; k4 < 4; ++k4)
      GLL16(BT + (size_t)(bn + srow + k4 * 64) * K + kt * 64 + ssw,
            &dst[(size_t)(tid + k4 * 512) * 8]);
  };

  auto tile = [&](int t, unsigned short* Acur, unsigned short* Bcur,
                  unsigned short* Anxt, unsigned short* Bnxt) {
    SBAR();  // all waves done reading the buffers we stage into
    if (t + 1 < nIter) {
      stA(Anxt, t + 1);
      stB(Bnxt, t + 1);
      WVM(8);  // completes THIS tile's 8 loads (issued last tile)
    } else {
      WVM(0);
    }
    SBAR();  // cross-wave: LDS for tile t ready
    // issue ALL fragment reads, pinned order: B(8), A-sec1(8), A-sec2(8)
    bf16x8 bfr[2][4], af1[2][4], af2[2][4];
#pragma unroll
    for (int kk = 0; kk < 2; ++kk)
#pragma unroll
      for (int ni = 0; ni < 4; ++ni) bfr[kk][ni] = LDBx(Bcur, ni, kk);
    SCHB();
#pragma unroll
    for (int kk = 0; kk < 2; ++kk)
#pragma unroll
      for (int m = 0; m < 4; ++m) af1[kk][m] = LDAx(Acur, m, kk);
    SCHB();
#pragma unroll
    for (int kk = 0; kk < 2; ++kk)
#pragma unroll
      for (int m = 0; m < 4; ++m) af2[kk][m] = LDAx(Acur, 4 + m, kk);
    WLGKM8();  // in-order DS: B + A-sec1 complete; A-sec2 drains under MFMAs
    __builtin_amdgcn_s_setprio(1);
#pragma unroll
    for (int kk = 0; kk < 2; ++kk)
#pragma unroll
      for (int m = 0; m < 4; ++m)
#pragma unroll
        for (int ni = 0; ni < 4; ++ni)
          acc[m][ni] = MFMA16(af1[kk][m], bfr[kk][ni], acc[m][ni], 0, 0, 0);
    __builtin_amdgcn_s_setprio(0);
    WLGKM0();
    __builtin_amdgcn_s_setprio(1);
#pragma unroll
    for (int kk = 0; kk < 2; ++kk)
#pragma unroll
      for (int m = 0; m < 4; ++m)
#pragma unroll
        for (int ni = 0; ni < 4; ++ni)
          acc[4 + m][ni] = MFMA16(af2[kk][m], bfr[kk][ni], acc[4 + m][ni], 0, 0, 0);
    __builtin_amdgcn_s_setprio(0);
  };

  // prologue: tile 0 into buf0
  stA(As0, 0);
  stB(Bs0, 0);

  for (int it = 0; it < nIter; it += 2) {
    tile(it, As0, Bs0, As1, Bs1);
    tile(it + 1, As1, Bs1, As0, Bs0);
  }

  const float SCLQ = 0.125f * 1.44269504088896f;
#pragma unroll
  for (int ni = 0; ni < 4; ++ni) {
    int col = bn + wn * 64 + ni * 16 + l15;
    float bs;
    if (OUTMODE == 4)
      bs = (col < 1024) ? bias1[col] : bias2[col - 1024];
    else
      bs = bias1[col];
#pragma unroll
    for (int mi = 0; mi < 8; ++mi) {
      int row0 = bm + wm * 128 + mi * 16 + (lq << 2);
      if (OUTMODE == 2) {
        int b_ = row0 >> 11, s0 = row0 & 2047;
        unsigned short* dst = (unsigned short*)out1 +
            ((size_t)((b_ * Hh + (col >> 7)) * DVv + (col & 127))) * Ss + s0;
        ushort4 o;
        o.x = f2b(acc[mi][ni][0] + bs);
        o.y = f2b(acc[mi][ni][1] + bs);
        o.z = f2b(acc[mi][ni][2] + bs);
        o.w = f2b(acc[mi][ni][3] + bs);
        *reinterpret_cast<ushort4*>(dst) = o;
      } else {  // OUTMODE == 4
        unsigned short* tgt = (unsigned short*)(col < 1024 ? out1 : out2);
        int cc = col & 1023, hh = cc >> 6, d = cc & 63;
#pragma unroll
        for (int r = 0; r < 4; ++r) {
          int row = row0 + r;
          int b_ = row >> 11, s0 = row & 2047;
          float v = acc[mi][ni][r] + bs;
          if (col < 1024) v *= SCLQ;
          tgt[(((size_t)(b_ * Hh + hh) * Ss + s0) << 6) + d] = f2b(v);
        }
      }
    }
  }
#undef LDAx
#undef LDBx
}

// ---------------------------------------------------------------------------
// gemm10f: 1-phase choreography, BM=256 BN=128, f32 out (out-projection).
// ---------------------------------------------------------------------------
__global__ __launch_bounds__(512, 2) void gemm10f_kernel(const unsigned short* __restrict__ A,
                                                         const unsigned short* __restrict__ BT,
                                                         const float* __restrict__ bias1,
                                                         float* __restrict__ out1,
                                                         int N, int K) {
  __shared__ unsigned short As0[256 * 64], As1[256 * 64];
  __shared__ unsigned short Bs0[128 * 64], Bs1[128 * 64];
  const int tid = threadIdx.x, wave = tid >> 6, lane = tid & 63;
  const int wm = wave >> 1, wn = wave & 1;
  const int l15 = lane & 15, lq = lane >> 4;
  const int nwg = gridDim.x, cpx = nwg >> 3;
  const int orig = (blockIdx.x & 7) * cpx + (blockIdx.x >> 3);
  const int bm = (orig & 31) << 8, bn = (orig >> 5) << 7;
  const int srow = tid >> 3;
  const int ssw = (((tid & 7) ^ (srow & 7)) << 3);
  const int rsw = l15 & 7;
  const int nIter = K >> 6;

  f32x4 acc[4][4] = {};

#define LDAf(P, MI, KK) \
  (*reinterpret_cast<const bf16x8*>(&(P)[(size_t)((wm * 64 + (MI)*16 + l15) * 64) + (((((KK)*4 + lq)) ^ rsw) << 3)]))
#define LDBf(P, NI, KK) \
  (*reinterpret_cast<const bf16x8*>(&(P)[(size_t)((wn * 64 + (NI)*16 + l15) * 64) + (((((KK)*4 + lq)) ^ rsw) << 3)]))

  auto stA = [&](unsigned short* dst, int kt) {
#pragma unroll
    for (int k4 = 0; k4 < 4; ++k4)
      GLL16(A + (size_t)(bm + srow + k4 * 64) * K + kt * 64 + ssw,
            &dst[(size_t)(tid + k4 * 512) * 8]);
  };
  auto stB = [&](unsigned short* dst, int kt) {
#pragma unroll
    for (int k4 = 0; k4 < 2; ++k4)
      GLL16(BT + (size_t)(bn + srow + k4 * 64) * K + kt * 64 + ssw,
            &dst[(size_t)(tid + k4 * 512) * 8]);
  };

  auto tile = [&](int t, unsigned short* Acur, unsigned short* Bcur,
                  unsigned short* Anxt, unsigned short* Bnxt) {
    SBAR();
    if (t + 1 < nIter) {
      stA(Anxt, t + 1);
      stB(Bnxt, t + 1);
      WVM(6);
    } else {
      WVM(0);
    }
    SBAR();
    bf16x8 bfr[2][4], af[2][4];
#pragma unroll
    for (int kk = 0; kk < 2; ++kk)
#pragma unroll
      for (int ni = 0; ni < 4; ++ni) bfr[kk][ni] = LDBf(Bcur, ni, kk);
#pragma unroll
    for (int kk = 0; kk < 2; ++kk)
#pragma unroll
      for (int m = 0; m < 4; ++m) af[kk][m] = LDAf(Acur, m, kk);
    WLGKM0();
    __builtin_amdgcn_s_setprio(1);
#pragma unroll
    for (int kk = 0; kk < 2; ++kk)
#pragma unroll
      for (int m = 0; m < 4; ++m)
#pragma unroll
        for (int ni = 0; ni < 4; ++ni)
          acc[m][ni] = MFMA16(af[kk][m], bfr[kk][ni], acc[m][ni], 0, 0, 0);
    __builtin_amdgcn_s_setprio(0);
  };

  stA(As0, 0);
  stB(Bs0, 0);

  for (int it = 0; it < nIter; it += 2) {
    tile(it, As0, Bs0, As1, Bs1);
    tile(it + 1, As1, Bs1, As0, Bs0);
  }

#pragma unroll
  for (int ni = 0; ni < 4; ++ni) {
    int col = bn + wn * 64 + ni * 16 + l15;
    float bs = bias1[col];
#pragma unroll
    for (int mi = 0; mi < 4; ++mi) {
      int row0 = bm + wm * 64 + mi * 16 + (lq << 2);
#pragma unroll
      for (int r = 0; r < 4; ++r)
        out1[(size_t)(row0 + r) * N + col] = acc[mi][ni][r] + bs;
    }
  }
#undef LDAf
#undef LDBf
}

// ---------------------------------------------------------------------------
// attn14 (round-18/20, proven 104 us): pair-balanced grid 256, 128-kv tiles,
// 16-chunk V swizzle, 32x32 MFMA, T12 in-register P, serial row-sum.
// ---------------------------------------------------------------------------
__global__ __launch_bounds__(512, 1) void attn14_kernel(const unsigned short* __restrict__ Qh,
                                                        const unsigned short* __restrict__ Kh,
                                                        const unsigned short* __restrict__ Vt,
                                                        unsigned short* __restrict__ Aw) {
  __shared__ unsigned short Kb[2][128 * 64];    // [kv][d], 8-chunk swz ^(kv&7)
  __shared__ unsigned short Vb[2][128 * 128];   // [dv][kv], 16-chunk swz ^(dv&15)
  const int bid = blockIdx.x;
  const int xcd = bid & 7, sub_ = bid >> 3;
  const int bhL = sub_ >> 2, q = sub_ & 3;
  const int bh = xcd + (bhL << 3);
  const int b = bh >> 4, h = bh & 15;
  const int tid = threadIdx.x, wave = tid >> 6, lane = tid & 63;
  const int l31 = lane & 31, lh = lane >> 5;

  const unsigned short* Qsrc = Qh + (size_t)(b * Hh + h) * Ss * DKk;
  const unsigned short* Ksrc = Kh + (size_t)(b * Hh + h) * Ss * DKk;
  const unsigned short* Vsrc = Vt + (size_t)(b * Hh + h) * (size_t)DVv * Ss;
  unsigned short* Adst = Aw + (size_t)b * Ss * NV + h * DVv;

  const int srowK = tid >> 3, schK = tid & 7;
  const int srowV = tid >> 4, schV = tid & 15;
  const int rx = l31 & 7;
  const int rxv = l31 & 15;

  union PU { unsigned u[4]; bf16x8 v; };

#pragma unroll 1
  for (int ph = 0; ph < 2; ++ph) {
    const int qt = ph ? q : 7 - q;
    const int nt2 = (qt + 1) * 2;
    const int q0w = qt * 256 + wave * 32;

    bf16x8 qf[4];
#pragma unroll
    for (int ks = 0; ks < 4; ++ks)
      qf[ks] = *reinterpret_cast<const bf16x8*>(
          Qsrc + (size_t)(q0w + l31) * DKk + ks * 16 + lh * 8);

    f32x16 accO[4] = {};
    float mrow = -1e30f, lrow = 0.f;

    {
#pragma unroll
      for (int k4 = 0; k4 < 2; ++k4) {
        int kvr = srowK + k4 * 64;
        GLL16(Ksrc + (size_t)kvr * DKk + ((schK ^ (kvr & 7)) << 3),
              &Kb[0][(size_t)(tid + k4 * 512) * 8]);
      }
#pragma unroll
      for (int k4 = 0; k4 < 4; ++k4) {
        int dvr = srowV + k4 * 32;
        GLL16(Vsrc + (size_t)dvr * Ss + ((schV ^ (dvr & 15)) << 3),
              &Vb[0][(size_t)(tid + k4 * 512) * 8]);
      }
    }

    for (int T = 0; T < nt2; ++T) {
      const int cur = T & 1;
      __syncthreads();
      if (T + 1 < nt2) {
        const int nb2 = (T + 1) * 128;
        const int nxt = cur ^ 1;
#pragma unroll
        for (int k4 = 0; k4 < 2; ++k4) {
          int kvr = srowK + k4 * 64;
          GLL16(Ksrc + (size_t)(nb2 + kvr) * DKk + ((schK ^ (kvr & 7)) << 3),
                &Kb[nxt][(size_t)(tid + k4 * 512) * 8]);
        }
#pragma unroll
        for (int k4 = 0; k4 < 4; ++k4) {
          int dvr = srowV + k4 * 32;
          GLL16(Vsrc + (size_t)dvr * Ss + nb2 + ((schV ^ (dvr & 15)) << 3),
                &Vb[nxt][(size_t)(tid + k4 * 512) * 8]);
        }
      }
#pragma unroll 1
      for (int sub = 0; sub < 2; ++sub) {
        const int kbase = T * 128 + sub * 64;
        if (kbase > q0w + 31) continue;

        f32x16 accS[2] = {};
        __builtin_amdgcn_s_setprio(1);
#pragma unroll
        for (int kvb = 0; kvb < 2; ++kvb)
#pragma unroll
          for (int ks = 0; ks < 4; ++ks) {
            const int row = sub * 64 + kvb * 32 + l31;
            bf16x8 kf = *reinterpret_cast<const bf16x8*>(
                &Kb[cur][row * 64 + (((ks * 2 + lh) ^ rx) << 3)]);
            accS[kvb] = MFMA32(kf, qf[ks], accS[kvb], 0, 0, 0);
          }
        __builtin_amdgcn_s_setprio(0);

        if (kbase + 63 > q0w) {
          int qg = q0w + l31;
#pragma unroll
          for (int kvb = 0; kvb < 2; ++kvb)
#pragma unroll
            for (int reg = 0; reg < 16; ++reg) {
              int kvg = kbase + kvb * 32 + (reg & 3) + 8 * (reg >> 2) + 4 * lh;
              if (kvg > qg) accS[kvb][reg] = -1e30f;
            }
        }
        float t[8];
#pragma unroll
        for (int i = 0; i < 8; ++i)
          t[i] = fmaxf(fmaxf(accS[0][i], accS[0][i + 8]), fmaxf(accS[1][i], accS[1][i + 8]));
        float pmx = fmaxf(fmaxf(fmaxf(t[0], t[1]), fmaxf(t[2], t[3])),
                          fmaxf(fmaxf(t[4], t[5]), fmaxf(t[6], t[7])));
        pmx = fmaxf(pmx, __shfl_xor(pmx, 32));
        float mn = mrow;
        if (!__all(pmx - mn <= 8.f)) {  // T13 defer-max
          float mnew = fmaxf(mn, pmx);
          float al = exp2f(mn - mnew);
          mrow = mnew;
          lrow *= al;
#pragma unroll
          for (int reg = 0; reg < 16; ++reg) {
            float a = __shfl(al, (reg & 3) + 8 * (reg >> 2) + 4 * lh);
#pragma unroll
            for (int dvb = 0; dvb < 4; ++dvb) accO[dvb][reg] *= a;
          }
          mn = mnew;
        }
        float rs = 0.f;
#pragma unroll
        for (int kvb = 0; kvb < 2; ++kvb)
#pragma unroll
          for (int reg = 0; reg < 16; ++reg) {
            float e = exp2f(accS[kvb][reg] - mn);
            accS[kvb][reg] = e;
            rs += e;
          }
        rs += __shfl_xor(rs, 32);
        lrow += rs;
        bf16x8 pfrag[4];
#pragma unroll
        for (int kvb = 0; kvb < 2; ++kvb)
#pragma unroll
          for (int s = 0; s < 2; ++s) {
            const int B0 = s * 8;
            unsigned a, c, bb, d;
            asm("v_cvt_pk_bf16_f32 %0, %1, %2" : "=v"(a) : "v"(accS[kvb][B0 + 0]), "v"(accS[kvb][B0 + 1]));
            asm("v_cvt_pk_bf16_f32 %0, %1, %2" : "=v"(c) : "v"(accS[kvb][B0 + 2]), "v"(accS[kvb][B0 + 3]));
            asm("v_cvt_pk_bf16_f32 %0, %1, %2" : "=v"(bb) : "v"(accS[kvb][B0 + 4]), "v"(accS[kvb][B0 + 5]));
            asm("v_cvt_pk_bf16_f32 %0, %1, %2" : "=v"(d) : "v"(accS[kvb][B0 + 6]), "v"(accS[kvb][B0 + 7]));
            asm volatile("v_permlane32_swap_b32 %0, %1" : "+v"(a), "+v"(bb));
            asm volatile("v_permlane32_swap_b32 %0, %1" : "+v"(c), "+v"(d));
            PU u;
            u.u[0] = a; u.u[1] = c; u.u[2] = bb; u.u[3] = d;
            pfrag[kvb * 2 + s] = u.v;
          }
        __builtin_amdgcn_s_setprio(1);
#pragma unroll
        for (int dvb = 0; dvb < 4; ++dvb) {
          const int dv = dvb * 32 + l31;
          const unsigned short* vr = &Vb[cur][dv * 128];
#pragma unroll
          for (int ks = 0; ks < 4; ++ks) {
            bf16x8 vf = *reinterpret_cast<const bf16x8*>(
                vr + ((((sub << 3) + ks * 2 + lh) ^ rxv) << 3));
            accO[dvb] = MFMA32(pfrag[ks], vf, accO[dvb], 0, 0, 0);
          }
        }
        __builtin_amdgcn_s_setprio(0);
      }
    }
    float linv = 1.f / lrow;
#pragma unroll
    for (int reg = 0; reg < 16; ++reg) {
      int qr = (reg & 3) + 8 * (reg >> 2) + 4 * lh;
      float li = __shfl(linv, qr);
      int row = q0w + qr;
#pragma unroll
      for (int dvb = 0; dvb < 4; ++dvb)
        Adst[(size_t)row * NV + dvb * 32 + l31] = f2b(accO[dvb][reg] * li);
    }
    __syncthreads();  // LDS reuse by next phase
  }
}

extern "C" void kernel_launch(void* const* d_in, const int* in_sizes, int n_in,
                              void* d_out, int out_size, void* d_ws, size_t ws_size,
                              hipStream_t stream) {
  (void)in_sizes; (void)n_in; (void)out_size; (void)ws_size;
  const float* x  = (const float*)d_in[0];
  const float* Wq = (const float*)d_in[1];
  const float* bq = (const float*)d_in[2];
  const float* Wk = (const float*)d_in[3];
  const float* bk = (const float*)d_in[4];
  const float* Wv = (const float*)d_in[5];
  const float* bv = (const float*)d_in[6];
  const float* Wo = (const float*)d_in[7];
  const float* bo = (const float*)d_in[8];
  float* out = (float*)d_out;

  unsigned short* ws = (unsigned short*)d_ws;
  unsigned short* xb  = ws;                    // 8388608  (x bf16 [8192][1024])
  unsigned short* WqT = xb  + 8388608;         // 1048576  } contiguous QK BT
  unsigned short* WkT = WqT + 1048576;         // 1048576  } [2048][1024]
  unsigned short* WvT = WkT + 1048576;         // 2097152  ([H*DV][E])
  unsigned short* WoT = WvT + 2097152;         // 2097152  ([E][H*DV])
  unsigned short* Qw  = WoT + 2097152;         // 8388608  ([B,H,S,64], pre-scaled)
  unsigned short* Kw  = Qw  + 8388608;         // 8388608  ([B,H,S,64])
  unsigned short* Vtw = Kw  + 8388608;         // 16777216 ([B,H,128,S])
  unsigned short* Aw  = Vtw + 16777216;        // 16777216 ([B,S,H*DV])

  cast_x_kernel<<<dim3(8192), dim3(256), 0, stream>>>(x, xb, (Mm * Ee) / 4);

  transpose_cast_kernel<<<dim3(2, 32, 16), dim3(32, 8), 0, stream>>>(Wq, WqT, Ee, DKk);
  transpose_cast_kernel<<<dim3(2, 32, 16), dim3(32, 8), 0, stream>>>(Wk, WkT, Ee, DKk);
  transpose_cast_kernel<<<dim3(4, 32, 16), dim3(32, 8), 0, stream>>>(Wv, WvT, Ee, DVv);
  transpose_cast_kernel<<<dim3(32, 64, 1), dim3(32, 8), 0, stream>>>(Wo, WoT, NV, Ee);

  gemm10_kernel<4><<<dim3(256), dim3(512), 0, stream>>>(xb, WqT, bq, bk, Qw, Kw, 2048, Ee);
  gemm10_kernel<2><<<dim3(256), dim3(512), 0, stream>>>(xb, WvT, bv, nullptr, Vtw, nullptr, NV, Ee);

  attn14_kernel<<<dim3(256), dim3(512), 0, stream>>>(Qw, Kw, Vtw, Aw);

  gemm10f_kernel<<<dim3(256), dim3(512), 0, stream>>>(Aw, WoT, bo, out, NQ, NV);
}

// Round 22
// 245.629 us; speedup vs baseline: 1.1029x; 1.1029x over previous
//
#include <hip/hip_runtime.h>

typedef __bf16 bf16x8 __attribute__((ext_vector_type(8)));
typedef float f32x4 __attribute__((ext_vector_type(4)));
typedef float f32x16 __attribute__((ext_vector_type(16)));

static constexpr int Bb = 4, Ss = 2048, Ee = 1024, Hh = 16, DKk = 64, DVv = 128;
static constexpr int Mm = Bb * Ss;   // 8192
static constexpr int NQ = Hh * DKk;  // 1024
static constexpr int NV = Hh * DVv;  // 2048

#define MFMA16 __builtin_amdgcn_mfma_f32_16x16x32_bf16
#define MFMA32 __builtin_amdgcn_mfma_f32_32x32x16_bf16

#define GLL16(g, l) __builtin_amdgcn_global_load_lds(                        \
    (const __attribute__((address_space(1))) void*)(g),                      \
    (__attribute__((address_space(3))) void*)(l), 16, 0, 0)

#define SBAR()   asm volatile("s_barrier" ::: "memory")
#define WLGKM0() do { asm volatile("s_waitcnt lgkmcnt(0)" ::: "memory"); \
                      __builtin_amdgcn_sched_barrier(0); } while (0)
#define WVM(n)   asm volatile("s_waitcnt vmcnt(" #n ")" ::: "memory")

static __device__ __forceinline__ unsigned short f2b(float f) {
  unsigned int u = __float_as_uint(f);
  u += 0x7fffu + ((u >> 16) & 1u);
  return (unsigned short)(u >> 16);
}

__global__ __launch_bounds__(256) void cast_x_kernel(const float* __restrict__ in,
                                                     unsigned short* __restrict__ out, int n4) {
  int i = blockIdx.x * 256 + threadIdx.x;
  if (i >= n4) return;
  float4 v = reinterpret_cast<const float4*>(in)[i];
  ushort4 o;
  o.x = f2b(v.x); o.y = f2b(v.y); o.z = f2b(v.z); o.w = f2b(v.w);
  reinterpret_cast<ushort4*>(out)[i] = o;
}

// in: [Bt][R][C] f32  ->  out: [Bt][C][R] bf16
__global__ __launch_bounds__(256) void transpose_cast_kernel(const float* __restrict__ in,
                                                             unsigned short* __restrict__ out,
                                                             int R, int C) {
  __shared__ float tile[32][33];
  int c0 = blockIdx.x * 32, r0 = blockIdx.y * 32;
  const float* ip = in + (size_t)blockIdx.z * R * C;
  unsigned short* op = out + (size_t)blockIdx.z * R * C;
  int tx = threadIdx.x, ty = threadIdx.y;
#pragma unroll
  for (int i = 0; i < 32; i += 8)
    tile[ty + i][tx] = ip[(size_t)(r0 + ty + i) * C + (c0 + tx)];
  __syncthreads();
#pragma unroll
  for (int i = 0; i < 32; i += 8)
    op[(size_t)(c0 + ty + i) * R + (r0 + tx)] = f2b(tile[tx][ty + i]);
}

// ---------------------------------------------------------------------------
// gemm10 (round-20 exact, best measured): 256x256 tile, ONE phase per
// 64-K-tile, 64 MFMA per barrier-pair, counted WVM(8), plain lgkm0 reads.
// Round-21 lesson: counted-lgkm fragment pipelining (+32 VGPR liveness +
// sched_barrier pins) regresses — do not re-apply.
// OUTMODE: 2 = bf16 Vt[B,H,DV,S]; 4 = fused QK head-major, Q pre-scaled.
// ---------------------------------------------------------------------------
template <int OUTMODE>
__global__ __launch_bounds__(512, 2) void gemm10_kernel(const unsigned short* __restrict__ A,
                                                        const unsigned short* __restrict__ BT,
                                                        const float* __restrict__ bias1,
                                                        const float* __restrict__ bias2,
                                                        void* __restrict__ out1,
                                                        void* __restrict__ out2,
                                                        int N, int K) {
  __shared__ unsigned short As0[256 * 64], As1[256 * 64];
  __shared__ unsigned short Bs0[256 * 64], Bs1[256 * 64];
  const int tid = threadIdx.x, wave = tid >> 6, lane = tid & 63;
  const int wm = wave >> 2, wn = wave & 3;
  const int l15 = lane & 15, lq = lane >> 4;
  const int nwg = gridDim.x, cpx = nwg >> 3;
  const int orig = (blockIdx.x & 7) * cpx + (blockIdx.x >> 3);  // XCD-contiguous
  const int bm = (orig & 31) << 8, bn = (orig >> 5) << 8;
  const int srow = tid >> 3;
  const int ssw = (((tid & 7) ^ (srow & 7)) << 3);
  const int rsw = l15 & 7;
  const int nIter = K >> 6;   // 64-K tiles

  f32x4 acc[8][4] = {};

#define LDAx(P, MI, KK) \
  (*reinterpret_cast<const bf16x8*>(&(P)[(size_t)((wm * 128 + (MI)*16 + l15) * 64) + (((((KK)*4 + lq)) ^ rsw) << 3)]))
#define LDBx(P, NI, KK) \
  (*reinterpret_cast<const bf16x8*>(&(P)[(size_t)((wn * 64 + (NI)*16 + l15) * 64) + (((((KK)*4 + lq)) ^ rsw) << 3)]))

  auto stA = [&](unsigned short* dst, int kt) {
#pragma unroll
    for (int k4 = 0; k4 < 4; ++k4)
      GLL16(A + (size_t)(bm + srow + k4 * 64) * K + kt * 64 + ssw,
            &dst[(size_t)(tid + k4 * 512) * 8]);
  };
  auto stB = [&](unsigned short* dst, int kt) {
#pragma unroll
    for (int k4 = 0; k4 < 4; ++k4)
      GLL16(BT + (size_t)(bn + srow + k4 * 64) * K + kt * 64 + ssw,
            &dst[(size_t)(tid + k4 * 512) * 8]);
  };

  auto tile = [&](int t, unsigned short* Acur, unsigned short* Bcur,
                  unsigned short* Anxt, unsigned short* Bnxt) {
    SBAR();  // all waves done reading the buffers we stage into
    if (t + 1 < nIter) {
      stA(Anxt, t + 1);
      stB(Bnxt, t + 1);
      WVM(8);  // completes THIS tile's 8 loads (issued last tile)
    } else {
      WVM(0);
    }
    SBAR();  // cross-wave: LDS for tile t ready
    bf16x8 bfr[2][4], af[2][4];
#pragma unroll
    for (int kk = 0; kk < 2; ++kk)
#pragma unroll
      for (int ni = 0; ni < 4; ++ni) bfr[kk][ni] = LDBx(Bcur, ni, kk);
#pragma unroll
    for (int kk = 0; kk < 2; ++kk)
#pragma unroll
      for (int m = 0; m < 4; ++m) af[kk][m] = LDAx(Acur, m, kk);
    WLGKM0();
    __builtin_amdgcn_s_setprio(1);
#pragma unroll
    for (int kk = 0; kk < 2; ++kk)
#pragma unroll
      for (int m = 0; m < 4; ++m)
#pragma unroll
        for (int ni = 0; ni < 4; ++ni)
          acc[m][ni] = MFMA16(af[kk][m], bfr[kk][ni], acc[m][ni], 0, 0, 0);
    __builtin_amdgcn_s_setprio(0);
#pragma unroll
    for (int kk = 0; kk < 2; ++kk)
#pragma unroll
      for (int m = 0; m < 4; ++m) af[kk][m] = LDAx(Acur, 4 + m, kk);
    WLGKM0();
    __builtin_amdgcn_s_setprio(1);
#pragma unroll
    for (int kk = 0; kk < 2; ++kk)
#pragma unroll
      for (int m = 0; m < 4; ++m)
#pragma unroll
        for (int ni = 0; ni < 4; ++ni)
          acc[4 + m][ni] = MFMA16(af[kk][m], bfr[kk][ni], acc[4 + m][ni], 0, 0, 0);
    __builtin_amdgcn_s_setprio(0);
  };

  // prologue: tile 0 into buf0
  stA(As0, 0);
  stB(Bs0, 0);

  for (int it = 0; it < nIter; it += 2) {
    tile(it, As0, Bs0, As1, Bs1);
    tile(it + 1, As1, Bs1, As0, Bs0);
  }

  const float SCLQ = 0.125f * 1.44269504088896f;
#pragma unroll
  for (int ni = 0; ni < 4; ++ni) {
    int col = bn + wn * 64 + ni * 16 + l15;
    float bs;
    if (OUTMODE == 4)
      bs = (col < 1024) ? bias1[col] : bias2[col - 1024];
    else
      bs = bias1[col];
#pragma unroll
    for (int mi = 0; mi < 8; ++mi) {
      int row0 = bm + wm * 128 + mi * 16 + (lq << 2);
      if (OUTMODE == 2) {
        int b_ = row0 >> 11, s0 = row0 & 2047;
        unsigned short* dst = (unsigned short*)out1 +
            ((size_t)((b_ * Hh + (col >> 7)) * DVv + (col & 127))) * Ss + s0;
        ushort4 o;
        o.x = f2b(acc[mi][ni][0] + bs);
        o.y = f2b(acc[mi][ni][1] + bs);
        o.z = f2b(acc[mi][ni][2] + bs);
        o.w = f2b(acc[mi][ni][3] + bs);
        *reinterpret_cast<ushort4*>(dst) = o;
      } else {  // OUTMODE == 4
        unsigned short* tgt = (unsigned short*)(col < 1024 ? out1 : out2);
        int cc = col & 1023, hh = cc >> 6, d = cc & 63;
#pragma unroll
        for (int r = 0; r < 4; ++r) {
          int row = row0 + r;
          int b_ = row >> 11, s0 = row & 2047;
          float v = acc[mi][ni][r] + bs;
          if (col < 1024) v *= SCLQ;
          tgt[(((size_t)(b_ * Hh + hh) * Ss + s0) << 6) + d] = f2b(v);
        }
      }
    }
  }
#undef LDAx
#undef LDBx
}

// ---------------------------------------------------------------------------
// gemm10f: same 1-phase choreography, BM=256 BN=128, f32 out (out-projection).
// ---------------------------------------------------------------------------
__global__ __launch_bounds__(512, 2) void gemm10f_kernel(const unsigned short* __restrict__ A,
                                                         const unsigned short* __restrict__ BT,
                                                         const float* __restrict__ bias1,
                                                         float* __restrict__ out1,
                                                         int N, int K) {
  __shared__ unsigned short As0[256 * 64], As1[256 * 64];
  __shared__ unsigned short Bs0[128 * 64], Bs1[128 * 64];
  const int tid = threadIdx.x, wave = tid >> 6, lane = tid & 63;
  const int wm = wave >> 1, wn = wave & 1;
  const int l15 = lane & 15, lq = lane >> 4;
  const int nwg = gridDim.x, cpx = nwg >> 3;
  const int orig = (blockIdx.x & 7) * cpx + (blockIdx.x >> 3);
  const int bm = (orig & 31) << 8, bn = (orig >> 5) << 7;
  const int srow = tid >> 3;
  const int ssw = (((tid & 7) ^ (srow & 7)) << 3);
  const int rsw = l15 & 7;
  const int nIter = K >> 6;

  f32x4 acc[4][4] = {};

#define LDAf(P, MI, KK) \
  (*reinterpret_cast<const bf16x8*>(&(P)[(size_t)((wm * 64 + (MI)*16 + l15) * 64) + (((((KK)*4 + lq)) ^ rsw) << 3)]))
#define LDBf(P, NI, KK) \
  (*reinterpret_cast<const bf16x8*>(&(P)[(size_t)((wn * 64 + (NI)*16 + l15) * 64) + (((((KK)*4 + lq)) ^ rsw) << 3)]))

  auto stA = [&](unsigned short* dst, int kt) {
#pragma unroll
    for (int k4 = 0; k4 < 4; ++k4)
      GLL16(A + (size_t)(bm + srow + k4 * 64) * K + kt * 64 + ssw,
            &dst[(size_t)(tid + k4 * 512) * 8]);
  };
  auto stB = [&](unsigned short* dst, int kt) {
#pragma unroll
    for (int k4 = 0; k4 < 2; ++k4)
      GLL16(BT + (size_t)(bn + srow + k4 * 64) * K + kt * 64 + ssw,
            &dst[(size_t)(tid + k4 * 512) * 8]);
  };

  auto tile = [&](int t, unsigned short* Acur, unsigned short* Bcur,
                  unsigned short* Anxt, unsigned short* Bnxt) {
    SBAR();
    if (t + 1 < nIter) {
      stA(Anxt, t + 1);
      stB(Bnxt, t + 1);
      WVM(6);
    } else {
      WVM(0);
    }
    SBAR();
    bf16x8 bfr[2][4], af[2][4];
#pragma unroll
    for (int kk = 0; kk < 2; ++kk)
#pragma unroll
      for (int ni = 0; ni < 4; ++ni) bfr[kk][ni] = LDBf(Bcur, ni, kk);
#pragma unroll
    for (int kk = 0; kk < 2; ++kk)
#pragma unroll
      for (int m = 0; m < 4; ++m) af[kk][m] = LDAf(Acur, m, kk);
    WLGKM0();
    __builtin_amdgcn_s_setprio(1);
#pragma unroll
    for (int kk = 0; kk < 2; ++kk)
#pragma unroll
      for (int m = 0; m < 4; ++m)
#pragma unroll
        for (int ni = 0; ni < 4; ++ni)
          acc[m][ni] = MFMA16(af[kk][m], bfr[kk][ni], acc[m][ni], 0, 0, 0);
    __builtin_amdgcn_s_setprio(0);
  };

  stA(As0, 0);
  stB(Bs0, 0);

  for (int it = 0; it < nIter; it += 2) {
    tile(it, As0, Bs0, As1, Bs1);
    tile(it + 1, As1, Bs1, As0, Bs0);
  }

#pragma unroll
  for (int ni = 0; ni < 4; ++ni) {
    int col = bn + wn * 64 + ni * 16 + l15;
    float bs = bias1[col];
#pragma unroll
    for (int mi = 0; mi < 4; ++mi) {
      int row0 = bm + wm * 64 + mi * 16 + (lq << 2);
#pragma unroll
      for (int r = 0; r < 4; ++r)
        out1[(size_t)(row0 + r) * N + col] = acc[mi][ni][r] + bs;
    }
  }
#undef LDAf
#undef LDBf
}

// ---------------------------------------------------------------------------
// attn14 (round-18/20, proven 104 us): pair-balanced grid 256, 128-kv tiles,
// 16-chunk V swizzle, 32x32 MFMA, T12 in-register P, serial row-sum.
// ---------------------------------------------------------------------------
__global__ __launch_bounds__(512, 1) void attn14_kernel(const unsigned short* __restrict__ Qh,
                                                        const unsigned short* __restrict__ Kh,
                                                        const unsigned short* __restrict__ Vt,
                                                        unsigned short* __restrict__ Aw) {
  __shared__ unsigned short Kb[2][128 * 64];    // [kv][d], 8-chunk swz ^(kv&7)
  __shared__ unsigned short Vb[2][128 * 128];   // [dv][kv], 16-chunk swz ^(dv&15)
  const int bid = blockIdx.x;
  const int xcd = bid & 7, sub_ = bid >> 3;
  const int bhL = sub_ >> 2, q = sub_ & 3;
  const int bh = xcd + (bhL << 3);
  const int b = bh >> 4, h = bh & 15;
  const int tid = threadIdx.x, wave = tid >> 6, lane = tid & 63;
  const int l31 = lane & 31, lh = lane >> 5;

  const unsigned short* Qsrc = Qh + (size_t)(b * Hh + h) * Ss * DKk;
  const unsigned short* Ksrc = Kh + (size_t)(b * Hh + h) * Ss * DKk;
  const unsigned short* Vsrc = Vt + (size_t)(b * Hh + h) * (size_t)DVv * Ss;
  unsigned short* Adst = Aw + (size_t)b * Ss * NV + h * DVv;

  const int srowK = tid >> 3, schK = tid & 7;
  const int srowV = tid >> 4, schV = tid & 15;
  const int rx = l31 & 7;
  const int rxv = l31 & 15;

  union PU { unsigned u[4]; bf16x8 v; };

#pragma unroll 1
  for (int ph = 0; ph < 2; ++ph) {
    const int qt = ph ? q : 7 - q;
    const int nt2 = (qt + 1) * 2;
    const int q0w = qt * 256 + wave * 32;

    bf16x8 qf[4];
#pragma unroll
    for (int ks = 0; ks < 4; ++ks)
      qf[ks] = *reinterpret_cast<const bf16x8*>(
          Qsrc + (size_t)(q0w + l31) * DKk + ks * 16 + lh * 8);

    f32x16 accO[4] = {};
    float mrow = -1e30f, lrow = 0.f;

    {
#pragma unroll
      for (int k4 = 0; k4 < 2; ++k4) {
        int kvr = srowK + k4 * 64;
        GLL16(Ksrc + (size_t)kvr * DKk + ((schK ^ (kvr & 7)) << 3),
              &Kb[0][(size_t)(tid + k4 * 512) * 8]);
      }
#pragma unroll
      for (int k4 = 0; k4 < 4; ++k4) {
        int dvr = srowV + k4 * 32;
        GLL16(Vsrc + (size_t)dvr * Ss + ((schV ^ (dvr & 15)) << 3),
              &Vb[0][(size_t)(tid + k4 * 512) * 8]);
      }
    }

    for (int T = 0; T < nt2; ++T) {
      const int cur = T & 1;
      __syncthreads();
      if (T + 1 < nt2) {
        const int nb2 = (T + 1) * 128;
        const int nxt = cur ^ 1;
#pragma unroll
        for (int k4 = 0; k4 < 2; ++k4) {
          int kvr = srowK + k4 * 64;
          GLL16(Ksrc + (size_t)(nb2 + kvr) * DKk + ((schK ^ (kvr & 7)) << 3),
                &Kb[nxt][(size_t)(tid + k4 * 512) * 8]);
        }
#pragma unroll
        for (int k4 = 0; k4 < 4; ++k4) {
          int dvr = srowV + k4 * 32;
          GLL16(Vsrc + (size_t)dvr * Ss + nb2 + ((schV ^ (dvr & 15)) << 3),
                &Vb[nxt][(size_t)(tid + k4 * 512) * 8]);
        }
      }
#pragma unroll 1
      for (int sub = 0; sub < 2; ++sub) {
        const int kbase = T * 128 + sub * 64;
        if (kbase > q0w + 31) continue;

        f32x16 accS[2] = {};
        __builtin_amdgcn_s_setprio(1);
#pragma unroll
        for (int kvb = 0; kvb < 2; ++kvb)
#pragma unroll
          for (int ks = 0; ks < 4; ++ks) {
            const int row = sub * 64 + kvb * 32 + l31;
            bf16x8 kf = *reinterpret_cast<const bf16x8*>(
                &Kb[cur][row * 64 + (((ks * 2 + lh) ^ rx) << 3)]);
            accS[kvb] = MFMA32(kf, qf[ks], accS[kvb], 0, 0, 0);
          }
        __builtin_amdgcn_s_setprio(0);

        if (kbase + 63 > q0w) {
          int qg = q0w + l31;
#pragma unroll
          for (int kvb = 0; kvb < 2; ++kvb)
#pragma unroll
            for (int reg = 0; reg < 16; ++reg) {
              int kvg = kbase + kvb * 32 + (reg & 3) + 8 * (reg >> 2) + 4 * lh;
              if (kvg > qg) accS[kvb][reg] = -1e30f;
            }
        }
        float t[8];
#pragma unroll
        for (int i = 0; i < 8; ++i)
          t[i] = fmaxf(fmaxf(accS[0][i], accS[0][i + 8]), fmaxf(accS[1][i], accS[1][i + 8]));
        float pmx = fmaxf(fmaxf(fmaxf(t[0], t[1]), fmaxf(t[2], t[3])),
                          fmaxf(fmaxf(t[4], t[5]), fmaxf(t[6], t[7])));
        pmx = fmaxf(pmx, __shfl_xor(pmx, 32));
        float mn = mrow;
        if (!__all(pmx - mn <= 8.f)) {  // T13 defer-max
          float mnew = fmaxf(mn, pmx);
          float al = exp2f(mn - mnew);
          mrow = mnew;
          lrow *= al;
#pragma unroll
          for (int reg = 0; reg < 16; ++reg) {
            float a = __shfl(al, (reg & 3) + 8 * (reg >> 2) + 4 * lh);
#pragma unroll
            for (int dvb = 0; dvb < 4; ++dvb) accO[dvb][reg] *= a;
          }
          mn = mnew;
        }
        float rs = 0.f;
#pragma unroll
        for (int kvb = 0; kvb < 2; ++kvb)
#pragma unroll
          for (int reg = 0; reg < 16; ++reg) {
            float e = exp2f(accS[kvb][reg] - mn);
            accS[kvb][reg] = e;
            rs += e;
          }
        rs += __shfl_xor(rs, 32);
        lrow += rs;
        bf16x8 pfrag[4];
#pragma unroll
        for (int kvb = 0; kvb < 2; ++kvb)
#pragma unroll
          for (int s = 0; s < 2; ++s) {
            const int B0 = s * 8;
            unsigned a, c, bb, d;
            asm("v_cvt_pk_bf16_f32 %0, %1, %2" : "=v"(a) : "v"(accS[kvb][B0 + 0]), "v"(accS[kvb][B0 + 1]));
            asm("v_cvt_pk_bf16_f32 %0, %1, %2" : "=v"(c) : "v"(accS[kvb][B0 + 2]), "v"(accS[kvb][B0 + 3]));
            asm("v_cvt_pk_bf16_f32 %0, %1, %2" : "=v"(bb) : "v"(accS[kvb][B0 + 4]), "v"(accS[kvb][B0 + 5]));
            asm("v_cvt_pk_bf16_f32 %0, %1, %2" : "=v"(d) : "v"(accS[kvb][B0 + 6]), "v"(accS[kvb][B0 + 7]));
            asm volatile("v_permlane32_swap_b32 %0, %1" : "+v"(a), "+v"(bb));
            asm volatile("v_permlane32_swap_b32 %0, %1" : "+v"(c), "+v"(d));
            PU u;
            u.u[0] = a; u.u[1] = c; u.u[2] = bb; u.u[3] = d;
            pfrag[kvb * 2 + s] = u.v;
          }
        __builtin_amdgcn_s_setprio(1);
#pragma unroll
        for (int dvb = 0; dvb < 4; ++dvb) {
          const int dv = dvb * 32 + l31;
          const unsigned short* vr = &Vb[cur][dv * 128];
#pragma unroll
          for (int ks = 0; ks < 4; ++ks) {
            bf16x8 vf = *reinterpret_cast<const bf16x8*>(
                vr + ((((sub << 3) + ks * 2 + lh) ^ rxv) << 3));
            accO[dvb] = MFMA32(pfrag[ks], vf, accO[dvb], 0, 0, 0);
          }
        }
        __builtin_amdgcn_s_setprio(0);
      }
    }
    float linv = 1.f / lrow;
#pragma unroll
    for (int reg = 0; reg < 16; ++reg) {
      int qr = (reg & 3) + 8 * (reg >> 2) + 4 * lh;
      float li = __shfl(linv, qr);
      int row = q0w + qr;
#pragma unroll
      for (int dvb = 0; dvb < 4; ++dvb)
        Adst[(size_t)row * NV + dvb * 32 + l31] = f2b(accO[dvb][reg] * li);
    }
    __syncthreads();  // LDS reuse by next phase
  }
}

extern "C" void kernel_launch(void* const* d_in, const int* in_sizes, int n_in,
                              void* d_out, int out_size, void* d_ws, size_t ws_size,
                              hipStream_t stream) {
  (void)in_sizes; (void)n_in; (void)out_size; (void)ws_size;
  const float* x  = (const float*)d_in[0];
  const float* Wq = (const float*)d_in[1];
  const float* bq = (const float*)d_in[2];
  const float* Wk = (const float*)d_in[3];
  const float* bk = (const float*)d_in[4];
  const float* Wv = (const float*)d_in[5];
  const float* bv = (const float*)d_in[6];
  const float* Wo = (const float*)d_in[7];
  const float* bo = (const float*)d_in[8];
  float* out = (float*)d_out;

  unsigned short* ws = (unsigned short*)d_ws;
  unsigned short* xb  = ws;                    // 8388608  (x bf16 [8192][1024])
  unsigned short* WqT = xb  + 8388608;         // 1048576  } contiguous QK BT
  unsigned short* WkT = WqT + 1048576;         // 1048576  } [2048][1024]
  unsigned short* WvT = WkT + 1048576;         // 2097152  ([H*DV][E])
  unsigned short* WoT = WvT + 2097152;         // 2097152  ([E][H*DV])
  unsigned short* Qw  = WoT + 2097152;         // 8388608  ([B,H,S,64], pre-scaled)
  unsigned short* Kw  = Qw  + 8388608;         // 8388608  ([B,H,S,64])
  unsigned short* Vtw = Kw  + 8388608;         // 16777216 ([B,H,128,S])
  unsigned short* Aw  = Vtw + 16777216;        // 16777216 ([B,S,H*DV])

  cast_x_kernel<<<dim3(8192), dim3(256), 0, stream>>>(x, xb, (Mm * Ee) / 4);

  transpose_cast_kernel<<<dim3(2, 32, 16), dim3(32, 8), 0, stream>>>(Wq, WqT, Ee, DKk);
  transpose_cast_kernel<<<dim3(2, 32, 16), dim3(32, 8), 0, stream>>>(Wk, WkT, Ee, DKk);
  transpose_cast_kernel<<<dim3(4, 32, 16), dim3(32, 8), 0, stream>>>(Wv, WvT, Ee, DVv);
  transpose_cast_kernel<<<dim3(32, 64, 1), dim3(32, 8), 0, stream>>>(Wo, WoT, NV, Ee);

  gemm10_kernel<4><<<dim3(256), dim3(512), 0, stream>>>(xb, WqT, bq, bk, Qw, Kw, 2048, Ee);
  gemm10_kernel<2><<<dim3(256), dim3(512), 0, stream>>>(xb, WvT, bv, nullptr, Vtw, nullptr, NV, Ee);

  attn14_kernel<<<dim3(256), dim3(512), 0, stream>>>(Qw, Kw, Vtw, Aw);

  gemm10f_kernel<<<dim3(256), dim3(512), 0, stream>>>(Aw, WoT, bo, out, NQ, NV);
}